// Round 11
// baseline (240.112 us; speedup 1.0000x reference)
//
#include <hip/hip_runtime.h>
#include <math.h>

#define NJ 960           // tail columns (global 64..1023)
#define NSRC 896         // tail sources (global 128..1023)
#define NWARM 25

typedef unsigned long long u64;
typedef unsigned int u32;

// ws u64 layout: RK[896]@0 | CT[960]@896 | HD[960]@1856 | BS[960]@2816 | DONE@3776
#define RK_O 0u
#define CT_O 896u
#define HD_O 1856u
#define BS_O 2816u
#define DN_O 3776u

#define TAG_RK 0x524B0001u
#define TAG_CT 0x43540001u
#define TAG_HD 0x48440001u
#define TAG_BS 0x42530001u

#define WAVE_FENCE __asm__ __volatile__("s_waitcnt lgkmcnt(0)" ::: "memory")

__device__ __forceinline__ void ast(u64* p, u64 v) {
  __hip_atomic_store(p, v, __ATOMIC_RELAXED, __HIP_MEMORY_SCOPE_AGENT);
}
__device__ __forceinline__ u64 ald(const u64* p) {
  return __hip_atomic_load(p, __ATOMIC_RELAXED, __HIP_MEMORY_SCOPE_AGENT);
}
__device__ __forceinline__ u32 poll32(const u64* p, u32 tag) {
  u64 v = ald(p);
  while ((u32)(v >> 32) != tag) { __builtin_amdgcn_s_sleep(1); v = ald(p); }
  return (u32)v;
}

struct BatchS {
  float At[64][66];
  float Wl[16][516];
  float bch[512];
  float pe[64], ne[64], pi2[64], ni2[64];   // e^{+-b E_k}, e^{+-b I_k}
};
struct FrontS {
  float4 TR[896];     // per-source transforms (EP,EN,IP,IN)
  float2 scE[960];    // scan buffer E (prefP, prefN)
  float2 scI[960];    // scan buffer I
  float4 colc[960];   // per-col (fm, fp, hd, bits(cntE|cntI<<16))
  float yl[960];      // current normalized state
};

__global__ __launch_bounds__(512, 4) void fused_k(
    const float* __restrict__ inp, const float* __restrict__ ident,
    const float* __restrict__ enh, const float* __restrict__ inh,
    const float* __restrict__ beta, const float* __restrict__ delta,
    void* __restrict__ wsv, float* __restrict__ out) {
  __shared__ __align__(16) char smraw[sizeof(BatchS) > sizeof(FrontS)
                                          ? sizeof(BatchS) : sizeof(FrontS)];

  u64* RK = (u64*)wsv + RK_O;
  u64* CT = (u64*)wsv + CT_O;
  u64* HD = (u64*)wsv + HD_O;
  u64* BS = (u64*)wsv + BS_O;
  u64* DN = (u64*)wsv + DN_O;

  const int tid = threadIdx.x;
  const int bid = blockIdx.x;
  const float bb = beta[0];
  const float dN = delta[0] / 1024.0f;

  // ================= block 0: single-wave scan warmup =================
  if (bid == 0) {
    if (tid >= 64) return;                 // one wave; NO barriers below
    __asm__ __volatile__("s_setprio 3");
    FrontS& F = *(FrontS*)smraw;
    const int lane = tid;

    u32 rEI[14];
    #pragma unroll
    for (int s = 0; s < 14; ++s) {
      int m = lane * 14 + s;
      rEI[s] = poll32(&RK[m], TAG_RK);
      float e = enh[128 + m], iv = inh[128 + m];
      F.TR[m] = make_float4(expf(bb * e), expf(-bb * e),
                            expf(bb * iv), expf(-bb * iv));
    }
    float y[15];
    #pragma unroll
    for (int c = 0; c < 15; ++c) {
      int j = lane * 15 + c;
      u32 ct = poll32(&CT[j], TAG_CT);
      float hdv = __uint_as_float(poll32(&HD[j], TAG_HD));
      float cj = ident[64 + j];
      F.colc[j] = make_float4(expf(-bb * cj), expf(bb * cj), hdv,
                              __uint_as_float(ct));
      y[c] = 1.0f / 1024.0f;
      F.yl[j] = 1.0f / 1024.0f;
    }
    WAVE_FENCE;

    for (int t = 0; t <= NWARM; ++t) {
      // phase 1: re-zero stale slots + scatter by precomputed rank
      if (lane < 63) {
        F.scE[897 + lane] = make_float2(0.f, 0.f);
        F.scI[897 + lane] = make_float2(0.f, 0.f);
      } else {
        F.scE[0] = make_float2(0.f, 0.f);
        F.scI[0] = make_float2(0.f, 0.f);
      }
      float ym[14];
      #pragma unroll
      for (int s = 0; s < 14; ++s) ym[s] = F.yl[64 + lane * 14 + s];
      #pragma unroll
      for (int s = 0; s < 14; ++s) {
        float4 tr = F.TR[lane * 14 + s];
        u32 r = rEI[s];
        F.scE[(r & 0xFFFF) + 1] = make_float2(ym[s] * tr.x, ym[s] * tr.y);
        F.scI[(r >> 16) + 1]    = make_float2(ym[s] * tr.z, ym[s] * tr.w);
      }
      WAVE_FENCE;

      // phase 2: local prefix + wave scan + writeback
      const int p0 = lane * 15;
      float2 pe[15], pi[15];
      #pragma unroll
      for (int i = 0; i < 15; ++i) { pe[i] = F.scE[p0 + i]; pi[i] = F.scI[p0 + i]; }
      #pragma unroll
      for (int i = 1; i < 15; ++i) {
        pe[i].x += pe[i - 1].x; pe[i].y += pe[i - 1].y;
        pi[i].x += pi[i - 1].x; pi[i].y += pi[i - 1].y;
      }
      float4 tot = make_float4(pe[14].x, pe[14].y, pi[14].x, pi[14].y);
      float4 inc = tot;
      #pragma unroll
      for (int off = 1; off < 64; off <<= 1) {
        float ox = __shfl_up(inc.x, off, 64);
        float oy = __shfl_up(inc.y, off, 64);
        float oz = __shfl_up(inc.z, off, 64);
        float ow = __shfl_up(inc.w, off, 64);
        if (lane >= off) { inc.x += ox; inc.y += oy; inc.z += oz; inc.w += ow; }
      }
      float4 exc = make_float4(inc.x - tot.x, inc.y - tot.y,
                               inc.z - tot.z, inc.w - tot.w);
      #pragma unroll
      for (int i = 0; i < 15; ++i) {
        pe[i].x += exc.x; pe[i].y += exc.y;
        pi[i].x += exc.z; pi[i].y += exc.w;
      }
      float TEy = __shfl(inc.y, 63);
      float TIy = __shfl(inc.w, 63);
      #pragma unroll
      for (int i = 0; i < 15; ++i) { F.scE[p0 + i] = pe[i]; F.scI[p0 + i] = pi[i]; }
      WAVE_FENCE;

      // phase 3: gather at precomputed counts + combine
      float nv[15];
      float psum = 0.0f;
      #pragma unroll
      for (int c = 0; c < 15; ++c) {
        int j = lane * 15 + c;
        float4 cc = F.colc[j];
        u32 ct = __float_as_uint(cc.w);
        float2 AE = F.scE[ct & 0xFFFF];
        float2 AI = F.scI[ct >> 16];
        float dot = cc.x * AE.x + cc.y * (TEy - AE.y)
                  - cc.x * AI.x - cc.y * (TIy - AI.y);
        float pre = y[c] + dN * dot;
        if (t < NWARM) {
          nv[c] = fmaxf(pre + cc.z, 0.0f);
          psum += nv[c];
        } else {
          ast(&BS[j], ((u64)TAG_BS << 32) | (u64)__float_as_uint(pre));
        }
      }
      if (t < NWARM) {
        #pragma unroll
        for (int off = 32; off >= 1; off >>= 1) psum += __shfl_xor(psum, off);
        float inv = (psum > 0.0f) ? 1.0f / psum : 1.0f;
        #pragma unroll
        for (int c = 0; c < 15; ++c) {
          y[c] = nv[c] * inv;
          F.yl[lane * 15 + c] = y[c];
        }
      }
      WAVE_FENCE;
    }
    // publish DONE: release (vmcnt(0) drain covers the wave's BS stores)
    if (lane == 0)
      __hip_atomic_store(DN, ((u64)TAG_BS << 32) | 1u,
                         __ATOMIC_RELEASE, __HIP_MEMORY_SCOPE_AGENT);
    return;
  }

  // ============ blocks 1..256: batch GEMM (1..15 do prep first) ============
  const int bx = bid - 1;                  // 0..255
  if (bid <= 15) {
    const int g = (bid - 1) * 512 + tid;   // 0..7679
    const int c8 = g & 7;
    if (g < NSRC * 8) {                    // A: source ranks
      int m = g >> 3;
      float myE = enh[128 + m], myI = inh[128 + m];
      int re = 0, ri = 0;
      for (int i = 112 * c8; i < 112 * c8 + 112; ++i) {
        float ev = enh[128 + i], iv = inh[128 + i];
        re += (ev < myE || (ev == myE && i < m)) ? 1 : 0;
        ri += (iv < myI || (iv == myI && i < m)) ? 1 : 0;
      }
      int p = re | (ri << 16);
      p += __shfl_xor(p, 1); p += __shfl_xor(p, 2); p += __shfl_xor(p, 4);
      if (c8 == 0) ast(&RK[m], ((u64)TAG_RK << 32) | (u32)p);
    }
    {                                      // B: per-column counts
      int j = g >> 3;
      float cj = ident[64 + j];
      int ce = 0, ci = 0;
      for (int i = 112 * c8; i < 112 * c8 + 112; ++i) {
        ce += (enh[128 + i] <= cj) ? 1 : 0;
        ci += (inh[128 + i] <= cj) ? 1 : 0;
      }
      int p = ce | (ci << 16);
      p += __shfl_xor(p, 1); p += __shfl_xor(p, 2); p += __shfl_xor(p, 4);
      if (c8 == 0) ast(&CT[j], ((u64)TAG_CT << 32) | (u32)p);
    }
    {                                      // C: head constants hd[j]
      int j = g >> 3;
      float cj = ident[64 + j];
      float h = 0.0f;
      for (int k = 8 * c8; k < 8 * c8 + 8; ++k)
        h += expf(-bb * fabsf(enh[k] - cj)) - expf(-bb * fabsf(inh[k] - cj));
      h += __shfl_xor(h, 1); h += __shfl_xor(h, 2); h += __shfl_xor(h, 4);
      if (c8 == 0)
        ast(&HD[j], ((u64)TAG_HD << 32) |
                    (u64)__float_as_uint(dN * h * (1.0f / 1024.0f)));
    }
  }

  BatchS& S = *(BatchS*)smraw;
  const int colg = tid & 63;
  const int rowg = tid >> 6;               // == wave id
  const size_t rowbase = (size_t)bx * 64;

  if (tid < 64) {                          // exp factors for W-gen min-trick
    float e = enh[tid], iv = inh[tid];
    S.pe[tid] = expf(bb * e);  S.ne[tid] = expf(-bb * e);
    S.pi2[tid] = expf(bb * iv); S.ni2[tid] = expf(-bb * iv);
  }
  #pragma unroll
  for (int i = 0; i < 2; ++i) {            // stage A^T
    int fi = tid + i * 512;
    int r = fi >> 4, c4 = (fi & 15) * 4;
    float4 f4 = *(const float4*)(inp + (rowbase + r) * 64 + c4);
    S.At[c4 + 0][r] = f4.x; S.At[c4 + 1][r] = f4.y;
    S.At[c4 + 2][r] = f4.z; S.At[c4 + 3][r] = f4.w;
  }

  // Micro-tile cols for lane colg: {4*colg..+3} and {256+4*colg..+3}
  // -> both Wl reads are consecutive-float4-per-lane = conflict-free b128.
  float rs[8];
  #pragma unroll
  for (int r = 0; r < 8; ++r) rs[r] = 0.0f;
  float acc[8][8];

  #pragma unroll 1
  for (int ch = 0; ch < 2; ++ch) {
    const int c0 = ch ? 0 : 512;           // output chunk LAST
    const int jme = c0 + tid;
    const bool ok = (jme < 960);
    const float cj = ok ? ident[64 + jme] : 0.0f;
    const float pj = expf(bb * cj), njx = expf(-bb * cj);
    #pragma unroll
    for (int r = 0; r < 8; ++r)
      #pragma unroll
      for (int c = 0; c < 8; ++c) acc[r][c] = 0.0f;

    #pragma unroll 1
    for (int s = 0; s < 4; ++s) {
      __syncthreads();                     // Wl readers done; staging visible
      #pragma unroll
      for (int i2 = 0; i2 < 16; ++i2) {    // W tile via min-of-products
        int k = 16 * s + i2;
        float v = 0.0f;
        if (ok)
          v = dN * (fminf(S.pe[k] * njx, S.ne[k] * pj) -
                    fminf(S.pi2[k] * njx, S.ni2[k] * pj));
        S.Wl[i2][tid] = v;
      }
      __syncthreads();

      #pragma unroll
      for (int kk = 0; kk < 16; ++kk) {
        float4 a0 = *(const float4*)&S.At[16 * s + kk][rowg * 8];
        float4 a1 = *(const float4*)&S.At[16 * s + kk][rowg * 8 + 4];
        float4 w0 = *(const float4*)&S.Wl[kk][4 * colg];         // cf b128
        float4 w1 = *(const float4*)&S.Wl[kk][256 + 4 * colg];   // cf b128
        float a[8] = {a0.x, a0.y, a0.z, a0.w, a1.x, a1.y, a1.z, a1.w};
        float w[8] = {w0.x, w0.y, w0.z, w0.w, w1.x, w1.y, w1.z, w1.w};
        #pragma unroll
        for (int r = 0; r < 8; ++r)
          #pragma unroll
          for (int c = 0; c < 8; ++c)
            acc[r][c] = fmaf(a[r], w[c], acc[r][c]);
      }
    }

    // wait ONCE (chunk 0 only): one lane polls the DONE flag, no storm
    if (ch == 0) {
      if (tid == 0) {
        u64 v = ald(DN);
        while ((u32)(v >> 32) != TAG_BS) {
          __builtin_amdgcn_s_sleep(32);
          v = ald(DN);
        }
      }
      __syncthreads();
    }
    // single tagged read per thread (guaranteed published)
    {
      float bv = -1.0e30f;
      if (ok) bv = __uint_as_float(poll32(&BS[jme], TAG_BS));
      S.bch[tid] = bv;
    }
    __syncthreads();
    #pragma unroll
    for (int c = 0; c < 8; ++c) {
      int cc = (c < 4) ? (4 * colg + c) : (256 + 4 * colg + c - 4);
      float bv = S.bch[cc];
      #pragma unroll
      for (int r = 0; r < 8; ++r)
        rs[r] += fmaxf(acc[r][c] + bv, 0.0f);
    }
  }

  #pragma unroll
  for (int r = 0; r < 8; ++r) {
    float v = rs[r];
    #pragma unroll
    for (int off = 32; off >= 1; off >>= 1) v += __shfl_xor(v, off);
    rs[r] = v;
  }

  // outputs: cols 0..63 of last chunk (c0=0) -> lanes colg<16, acc c=0..3
  if (colg < 16) {
    #pragma unroll
    for (int r = 0; r < 8; ++r) {
      float inv = (rs[r] > 0.0f) ? 1.0f / rs[r] : 1.0f;
      float* op = out + (rowbase + rowg * 8 + r) * 64 + 4 * colg;
      float4 o;
      o.x = fmaxf(acc[r][0] + S.bch[4 * colg + 0], 0.0f) * inv;
      o.y = fmaxf(acc[r][1] + S.bch[4 * colg + 1], 0.0f) * inv;
      o.z = fmaxf(acc[r][2] + S.bch[4 * colg + 2], 0.0f) * inv;
      o.w = fmaxf(acc[r][3] + S.bch[4 * colg + 3], 0.0f) * inv;
      *(float4*)op = o;
    }
  }
}

extern "C" void kernel_launch(void* const* d_in, const int* in_sizes, int n_in,
                              void* d_out, int out_size, void* d_ws, size_t ws_size,
                              hipStream_t stream) {
  const float* inp   = (const float*)d_in[0];
  const float* ident = (const float*)d_in[1];
  const float* enh   = (const float*)d_in[2];
  const float* inh   = (const float*)d_in[3];
  const float* beta  = (const float*)d_in[4];
  const float* delta = (const float*)d_in[5];

  hipLaunchKernelGGL(fused_k, dim3(257), dim3(512), 0, stream,
                     inp, ident, enh, inh, beta, delta, d_ws, (float*)d_out);
}

// Round 12
// 203.457 us; speedup vs baseline: 1.1802x; 1.1802x over previous
//
#include <hip/hip_runtime.h>
#include <math.h>

#define NJ 960           // tail columns (global 64..1023)
#define NSRC 896         // tail sources (global 128..1023)
#define NWARM 25

typedef unsigned long long u64;
typedef unsigned int u32;

// ws u64 layout: RK[896]@0 | CT[960]@896 | HD[960]@1856 | BS[960]@2816 | DONE@3776
#define RK_O 0u
#define CT_O 896u
#define HD_O 1856u
#define BS_O 2816u
#define DN_O 3776u

#define TAG_RK 0x524B0001u
#define TAG_CT 0x43540001u
#define TAG_HD 0x48440001u
#define TAG_BS 0x42530001u

#define WAVE_FENCE __asm__ __volatile__("s_waitcnt lgkmcnt(0)" ::: "memory")

__device__ __forceinline__ void ast(u64* p, u64 v) {
  __hip_atomic_store(p, v, __ATOMIC_RELAXED, __HIP_MEMORY_SCOPE_AGENT);
}
__device__ __forceinline__ u64 ald(const u64* p) {
  return __hip_atomic_load(p, __ATOMIC_RELAXED, __HIP_MEMORY_SCOPE_AGENT);
}
__device__ __forceinline__ u32 poll32(const u64* p, u32 tag) {
  u64 v = ald(p);
  while ((u32)(v >> 32) != tag) { __builtin_amdgcn_s_sleep(1); v = ald(p); }
  return (u32)v;
}

struct BatchS {
  float At[64][66];    // A^T staged
  float Wl[16][260];   // W k-slab for a 256-col chunk
  float bch[256];      // base for current chunk
  float pe[64], ne[64], pi2[64], ni2[64];   // e^{+-b E_k}, e^{+-b I_k}
};
struct FrontS {
  float4 TR[896];     // per-source transforms (EP,EN,IP,IN)
  float2 scE[960];    // scan buffer E (prefP, prefN)
  float2 scI[960];    // scan buffer I
  float4 colc[960];   // per-col (fm, fp, hd, bits(cntE|cntI<<16))
  float yl[960];      // current normalized state
};

__global__ __launch_bounds__(512, 2) void fused_k(
    const float* __restrict__ inp, const float* __restrict__ ident,
    const float* __restrict__ enh, const float* __restrict__ inh,
    const float* __restrict__ beta, const float* __restrict__ delta,
    void* __restrict__ wsv, float* __restrict__ out) {
  __shared__ __align__(16) char smraw[sizeof(BatchS) > sizeof(FrontS)
                                          ? sizeof(BatchS) : sizeof(FrontS)];

  u64* RK = (u64*)wsv + RK_O;
  u64* CT = (u64*)wsv + CT_O;
  u64* HD = (u64*)wsv + HD_O;
  u64* BS = (u64*)wsv + BS_O;
  u64* DN = (u64*)wsv + DN_O;

  const int tid = threadIdx.x;
  const int bid = blockIdx.x;
  const float bb = beta[0];
  const float dN = delta[0] / 1024.0f;

  // ================= block 0: single-wave scan warmup =================
  if (bid == 0) {
    if (tid >= 64) return;                 // one wave; NO barriers below
    __asm__ __volatile__("s_setprio 3");
    FrontS& F = *(FrontS*)smraw;
    const int lane = tid;

    u32 rEI[14];
    #pragma unroll
    for (int s = 0; s < 14; ++s) {
      int m = lane * 14 + s;
      rEI[s] = poll32(&RK[m], TAG_RK);
      float e = enh[128 + m], iv = inh[128 + m];
      F.TR[m] = make_float4(expf(bb * e), expf(-bb * e),
                            expf(bb * iv), expf(-bb * iv));
    }
    float y[15];
    #pragma unroll
    for (int c = 0; c < 15; ++c) {
      int j = lane * 15 + c;
      u32 ct = poll32(&CT[j], TAG_CT);
      float hdv = __uint_as_float(poll32(&HD[j], TAG_HD));
      float cj = ident[64 + j];
      F.colc[j] = make_float4(expf(-bb * cj), expf(bb * cj), hdv,
                              __uint_as_float(ct));
      y[c] = 1.0f / 1024.0f;
      F.yl[j] = 1.0f / 1024.0f;
    }
    WAVE_FENCE;

    for (int t = 0; t <= NWARM; ++t) {
      // phase 1: re-zero stale slots + scatter by precomputed rank
      if (lane < 63) {
        F.scE[897 + lane] = make_float2(0.f, 0.f);
        F.scI[897 + lane] = make_float2(0.f, 0.f);
      } else {
        F.scE[0] = make_float2(0.f, 0.f);
        F.scI[0] = make_float2(0.f, 0.f);
      }
      float ym[14];
      #pragma unroll
      for (int s = 0; s < 14; ++s) ym[s] = F.yl[64 + lane * 14 + s];
      #pragma unroll
      for (int s = 0; s < 14; ++s) {
        float4 tr = F.TR[lane * 14 + s];
        u32 r = rEI[s];
        F.scE[(r & 0xFFFF) + 1] = make_float2(ym[s] * tr.x, ym[s] * tr.y);
        F.scI[(r >> 16) + 1]    = make_float2(ym[s] * tr.z, ym[s] * tr.w);
      }
      WAVE_FENCE;

      // phase 2: local prefix + wave scan + writeback
      const int p0 = lane * 15;
      float2 pe[15], pi[15];
      #pragma unroll
      for (int i = 0; i < 15; ++i) { pe[i] = F.scE[p0 + i]; pi[i] = F.scI[p0 + i]; }
      #pragma unroll
      for (int i = 1; i < 15; ++i) {
        pe[i].x += pe[i - 1].x; pe[i].y += pe[i - 1].y;
        pi[i].x += pi[i - 1].x; pi[i].y += pi[i - 1].y;
      }
      float4 tot = make_float4(pe[14].x, pe[14].y, pi[14].x, pi[14].y);
      float4 inc = tot;
      #pragma unroll
      for (int off = 1; off < 64; off <<= 1) {
        float ox = __shfl_up(inc.x, off, 64);
        float oy = __shfl_up(inc.y, off, 64);
        float oz = __shfl_up(inc.z, off, 64);
        float ow = __shfl_up(inc.w, off, 64);
        if (lane >= off) { inc.x += ox; inc.y += oy; inc.z += oz; inc.w += ow; }
      }
      float4 exc = make_float4(inc.x - tot.x, inc.y - tot.y,
                               inc.z - tot.z, inc.w - tot.w);
      #pragma unroll
      for (int i = 0; i < 15; ++i) {
        pe[i].x += exc.x; pe[i].y += exc.y;
        pi[i].x += exc.z; pi[i].y += exc.w;
      }
      float TEy = __shfl(inc.y, 63);
      float TIy = __shfl(inc.w, 63);
      #pragma unroll
      for (int i = 0; i < 15; ++i) { F.scE[p0 + i] = pe[i]; F.scI[p0 + i] = pi[i]; }
      WAVE_FENCE;

      // phase 3: gather at precomputed counts + combine
      float nv[15];
      float psum = 0.0f;
      #pragma unroll
      for (int c = 0; c < 15; ++c) {
        int j = lane * 15 + c;
        float4 cc = F.colc[j];
        u32 ct = __float_as_uint(cc.w);
        float2 AE = F.scE[ct & 0xFFFF];
        float2 AI = F.scI[ct >> 16];
        float dot = cc.x * AE.x + cc.y * (TEy - AE.y)
                  - cc.x * AI.x - cc.y * (TIy - AI.y);
        float pre = y[c] + dN * dot;
        if (t < NWARM) {
          nv[c] = fmaxf(pre + cc.z, 0.0f);
          psum += nv[c];
        } else {
          ast(&BS[j], ((u64)TAG_BS << 32) | (u64)__float_as_uint(pre));
        }
      }
      if (t < NWARM) {
        #pragma unroll
        for (int off = 32; off >= 1; off >>= 1) psum += __shfl_xor(psum, off);
        float inv = (psum > 0.0f) ? 1.0f / psum : 1.0f;
        #pragma unroll
        for (int c = 0; c < 15; ++c) {
          y[c] = nv[c] * inv;
          F.yl[lane * 15 + c] = y[c];
        }
      }
      WAVE_FENCE;
    }
    // publish DONE: release (vmcnt(0) drain covers the wave's BS stores)
    if (lane == 0)
      __hip_atomic_store(DN, ((u64)TAG_BS << 32) | 1u,
                         __ATOMIC_RELEASE, __HIP_MEMORY_SCOPE_AGENT);
    return;
  }

  // ============ blocks 1..256: batch GEMM (1..15 do prep first) ============
  const int bx = bid - 1;                  // 0..255
  if (bid <= 15) {
    const int g = (bid - 1) * 512 + tid;   // 0..7679
    const int c8 = g & 7;
    if (g < NSRC * 8) {                    // A: source ranks
      int m = g >> 3;
      float myE = enh[128 + m], myI = inh[128 + m];
      int re = 0, ri = 0;
      for (int i = 112 * c8; i < 112 * c8 + 112; ++i) {
        float ev = enh[128 + i], iv = inh[128 + i];
        re += (ev < myE || (ev == myE && i < m)) ? 1 : 0;
        ri += (iv < myI || (iv == myI && i < m)) ? 1 : 0;
      }
      int p = re | (ri << 16);
      p += __shfl_xor(p, 1); p += __shfl_xor(p, 2); p += __shfl_xor(p, 4);
      if (c8 == 0) ast(&RK[m], ((u64)TAG_RK << 32) | (u32)p);
    }
    {                                      // B: per-column counts
      int j = g >> 3;
      float cj = ident[64 + j];
      int ce = 0, ci = 0;
      for (int i = 112 * c8; i < 112 * c8 + 112; ++i) {
        ce += (enh[128 + i] <= cj) ? 1 : 0;
        ci += (inh[128 + i] <= cj) ? 1 : 0;
      }
      int p = ce | (ci << 16);
      p += __shfl_xor(p, 1); p += __shfl_xor(p, 2); p += __shfl_xor(p, 4);
      if (c8 == 0) ast(&CT[j], ((u64)TAG_CT << 32) | (u32)p);
    }
    {                                      // C: head constants hd[j]
      int j = g >> 3;
      float cj = ident[64 + j];
      float h = 0.0f;
      for (int k = 8 * c8; k < 8 * c8 + 8; ++k)
        h += expf(-bb * fabsf(enh[k] - cj)) - expf(-bb * fabsf(inh[k] - cj));
      h += __shfl_xor(h, 1); h += __shfl_xor(h, 2); h += __shfl_xor(h, 4);
      if (c8 == 0)
        ast(&HD[j], ((u64)TAG_HD << 32) |
                    (u64)__float_as_uint(dN * h * (1.0f / 1024.0f)));
    }
  }

  BatchS& S = *(BatchS*)smraw;
  const int colg = tid & 63;
  const int rowg = tid >> 6;               // == wave id
  const size_t rowbase = (size_t)bx * 64;

  if (tid < 64) {                          // exp factors for W-gen min-trick
    float e = enh[tid], iv = inh[tid];
    S.pe[tid] = expf(bb * e);  S.ne[tid] = expf(-bb * e);
    S.pi2[tid] = expf(bb * iv); S.ni2[tid] = expf(-bb * iv);
  }
  #pragma unroll
  for (int i = 0; i < 2; ++i) {            // stage A^T
    int fi = tid + i * 512;
    int r = fi >> 4, c4 = (fi & 15) * 4;
    float4 f4 = *(const float4*)(inp + (rowbase + r) * 64 + c4);
    S.At[c4 + 0][r] = f4.x; S.At[c4 + 1][r] = f4.y;
    S.At[c4 + 2][r] = f4.z; S.At[c4 + 3][r] = f4.w;
  }

  // 4 chunks of 256 cols, order {256,512,768,0} (output chunk LAST).
  // Micro-tile: 8 rows (rowg, A broadcast) x 4 cols (one b128 at 4*colg).
  // W-gen: thread handles col=tid&255, k rows 2*i+(tid>>8) -> wave-uniform
  // S.pe[k] reads, conflict-free Wl writes.
  float rs[8];
  #pragma unroll
  for (int r = 0; r < 8; ++r) rs[r] = 0.0f;
  float acc[8][4];
  const int wc = tid & 255;                // W-gen column within chunk
  const int kh = tid >> 8;                 // 0/1: k parity

  #pragma unroll 1
  for (int ch = 0; ch < 4; ++ch) {
    const int c0 = (ch < 3) ? (ch + 1) * 256 : 0;
    const int jw = c0 + wc;
    const bool okw = (jw < 960);
    float pj = 1.0f, njx = 1.0f;
    if (okw) {
      float cj = ident[64 + jw];
      pj = expf(bb * cj); njx = expf(-bb * cj);
    }
    #pragma unroll
    for (int r = 0; r < 8; ++r)
      #pragma unroll
      for (int c = 0; c < 4; ++c) acc[r][c] = 0.0f;

    #pragma unroll 1
    for (int s = 0; s < 4; ++s) {
      __syncthreads();                     // Wl readers done; staging visible
      #pragma unroll
      for (int i2 = 0; i2 < 8; ++i2) {     // W tile via min-of-products
        int kk = 2 * i2 + kh;
        int k = 16 * s + kk;
        float v = 0.0f;
        if (okw)
          v = dN * (fminf(S.pe[k] * njx, S.ne[k] * pj) -
                    fminf(S.pi2[k] * njx, S.ni2[k] * pj));
        S.Wl[kk][wc] = v;
      }
      __syncthreads();

      #pragma unroll
      for (int kk = 0; kk < 16; ++kk) {
        float4 a0 = *(const float4*)&S.At[16 * s + kk][rowg * 8];     // bcast
        float4 a1 = *(const float4*)&S.At[16 * s + kk][rowg * 8 + 4]; // bcast
        float4 w0 = *(const float4*)&S.Wl[kk][4 * colg];              // cf b128
        float a[8] = {a0.x, a0.y, a0.z, a0.w, a1.x, a1.y, a1.z, a1.w};
        float w[4] = {w0.x, w0.y, w0.z, w0.w};
        #pragma unroll
        for (int r = 0; r < 8; ++r)
          #pragma unroll
          for (int c = 0; c < 4; ++c)
            acc[r][c] = fmaf(a[r], w[c], acc[r][c]);
      }
    }

    // first chunk: wait ONCE on the DONE flag (one lane, no storm)
    if (ch == 0) {
      if (tid == 0) {
        u64 v = ald(DN);
        while ((u32)(v >> 32) != TAG_BS) {
          __builtin_amdgcn_s_sleep(32);
          v = ald(DN);
        }
      }
      __syncthreads();
    }
    // per-chunk base: one tagged read per col (already published)
    if (tid < 256) {
      int j = c0 + tid;
      float bv = -1.0e30f;                 // pad cols -> relu 0
      if (j < 960) bv = __uint_as_float(poll32(&BS[j], TAG_BS));
      S.bch[tid] = bv;
    }
    __syncthreads();
    #pragma unroll
    for (int c = 0; c < 4; ++c) {
      float bv = S.bch[4 * colg + c];
      #pragma unroll
      for (int r = 0; r < 8; ++r)
        rs[r] += fmaxf(acc[r][c] + bv, 0.0f);
    }
  }

  #pragma unroll
  for (int r = 0; r < 8; ++r) {
    float v = rs[r];
    #pragma unroll
    for (int off = 32; off >= 1; off >>= 1) v += __shfl_xor(v, off);
    rs[r] = v;
  }

  // outputs: cols 0..63 of last chunk (c0=0) -> lanes colg<16, live acc
  if (colg < 16) {
    #pragma unroll
    for (int r = 0; r < 8; ++r) {
      float inv = (rs[r] > 0.0f) ? 1.0f / rs[r] : 1.0f;
      float* op = out + (rowbase + rowg * 8 + r) * 64 + 4 * colg;
      float4 o;
      o.x = fmaxf(acc[r][0] + S.bch[4 * colg + 0], 0.0f) * inv;
      o.y = fmaxf(acc[r][1] + S.bch[4 * colg + 1], 0.0f) * inv;
      o.z = fmaxf(acc[r][2] + S.bch[4 * colg + 2], 0.0f) * inv;
      o.w = fmaxf(acc[r][3] + S.bch[4 * colg + 3], 0.0f) * inv;
      *(float4*)op = o;
    }
  }
}

extern "C" void kernel_launch(void* const* d_in, const int* in_sizes, int n_in,
                              void* d_out, int out_size, void* d_ws, size_t ws_size,
                              hipStream_t stream) {
  const float* inp   = (const float*)d_in[0];
  const float* ident = (const float*)d_in[1];
  const float* enh   = (const float*)d_in[2];
  const float* inh   = (const float*)d_in[3];
  const float* beta  = (const float*)d_in[4];
  const float* delta = (const float*)d_in[5];

  hipLaunchKernelGGL(fused_k, dim3(257), dim3(512), 0, stream,
                     inp, ident, enh, inh, beta, delta, d_ws, (float*)d_out);
}